// Round 1
// 467.025 us; speedup vs baseline: 1.1413x; 1.1413x over previous
//
#include <hip/hip_runtime.h>

// x[8,25,256,256] (fp32) conv w[100,25,9,9] VALID -> out[8,100,248,248] (fp32)
// Implicit GEMM on bf16 MFMA 16x16x32.
// v2: per-ky LDS staging of the xt row (global_load_lds w=16, dbuf, barrier
// only at ky boundaries), ds_read_b128 b-frags, dynamic ky loop (I$-friendly),
// register-prefetched a-frags, merged prep kernel.

#define NB   8
#define NC   25
#define C32  32
#define NH   256
#define NW   256
#define NOC  100
#define MT   7      // 7 M-tiles of 16 -> 112 (oc padded)
#define KH_  9
#define KW_  9
#define OH   248
#define OW   248

typedef __attribute__((ext_vector_type(8))) short bf16x8;
typedef __attribute__((ext_vector_type(4))) float f32x4;

// ws layout: [wf: 81*7*64*8 bf16][pad to 1 MiB][xt: 8*256*256*32 bf16 = 33.5 MB]
#define WF_ELEMS   (KH_ * KW_ * MT * 64 * 8)          // 290,304
#define WF_BLOCKS  (WF_ELEMS / 256)                   // 1134 exact
#define XT_OFFSET  (1 << 20)

__device__ __forceinline__ unsigned short f2bf(float f) {
    unsigned u = __float_as_uint(f);
    return (unsigned short)((u + 0x7FFFu + ((u >> 16) & 1u)) >> 16);
}

// async global->LDS, 16B per lane; LDS dest = wave-uniform base + lane*16
__device__ __forceinline__ void gll16(const short* g, short* l) {
    __builtin_amdgcn_global_load_lds(
        (const __attribute__((address_space(1))) void*)g,
        (__attribute__((address_space(3))) void*)l, 16, 0, 0);
}

// ---- merged prep: [0, WF_BLOCKS) -> weights; rest -> xt transpose ----
// wf[(p*7 + mt)*64 + lane][j], p = ky*9+kx; A[m][k]: m = oc = mt*16+(lane&15),
// k = c = (lane>>4)*8 + j
// xt[b][y][x][c32] bf16 from x[b][c][y][x] fp32 via LDS transpose
__global__ __launch_bounds__(256)
void prep(const float* __restrict__ w, const float* __restrict__ x,
          short* __restrict__ wf, short* __restrict__ xt) {
    if (blockIdx.x < WF_BLOCKS) {
        int idx = blockIdx.x * 256 + threadIdx.x;
        if (idx >= WF_ELEMS) return;
        int j    = idx & 7;
        int lane = (idx >> 3) & 63;
        int rest = idx >> 9;
        int mt   = rest % MT;
        int p    = rest / MT;
        int ky   = p / KW_;
        int kx   = p % KW_;
        int oc   = mt * 16 + (lane & 15);
        int c    = (lane >> 4) * 8 + j;
        float v = 0.0f;
        if (oc < NOC && c < NC)
            v = w[(((size_t)oc * NC + c) * KH_ + ky) * KW_ + kx];
        wf[idx] = (short)f2bf(v);
    } else {
        __shared__ short row[NC][NW];          // 12.8 KB
        const int bid = blockIdx.x - WF_BLOCKS;
        const int b = bid >> 8;
        const int y = bid & 255;
        const float* src = x + ((size_t)b * NC) * NH * NW + (size_t)y * NW;

        // coalesced float4 loads: 25 rows x 64 float4
        for (int i = threadIdx.x; i < NC * 64; i += 256) {
            int c  = i >> 6;
            int xq = (i & 63) << 2;
            float4 v = *(const float4*)(src + (size_t)c * NH * NW + xq);
            unsigned short s[4] = { f2bf(v.x), f2bf(v.y), f2bf(v.z), f2bf(v.w) };
            *(unsigned long long*)&row[c][xq] = *(const unsigned long long*)s;
        }
        __syncthreads();

        const int xc = threadIdx.x;
        unsigned short v[C32];
        #pragma unroll
        for (int c = 0; c < NC; ++c) v[c] = (unsigned short)row[c][xc];
        #pragma unroll
        for (int c = NC; c < C32; ++c) v[c] = 0;
        short* dst = xt + (((size_t)b * NH + y) * NW + xc) * C32;
        #pragma unroll
        for (int i = 0; i < 4; ++i)
            ((int4*)dst)[i] = ((const int4*)v)[i];
    }
}

// ---- main: one block = one output row (b, oy); 4 waves x N=64; M=112 ----
#define LOADA(A, KX)                                                          \
    { _Pragma("unroll")                                                       \
      for (int mt = 0; mt < MT; ++mt)                                         \
          A[mt] = *(const bf16x8*)(wky + (KX) * 3584 + mt * 512); }

#define LOADB(B, KX)                                                          \
    { _Pragma("unroll")                                                       \
      for (int nt = 0; nt < 4; ++nt) {                                        \
          int col = colb + nt * 16 + (KX);                                    \
          col = col > 255 ? 255 : col;   /* only feeds masked-out cols */     \
          B[nt] = *(const bf16x8*)(lrow + col * C32 + quad * 8); } }

#define MM(A, B)                                                              \
    { _Pragma("unroll")                                                       \
      for (int nt = 0; nt < 4; ++nt)                                          \
          _Pragma("unroll")                                                   \
          for (int mt = 0; mt < MT; ++mt)                                     \
              acc[mt][nt] = __builtin_amdgcn_mfma_f32_16x16x32_bf16(          \
                  A[mt], B[nt], acc[mt][nt], 0, 0, 0); }

__global__ __launch_bounds__(256, 2)
void conv_mfma(const short* __restrict__ wf, const short* __restrict__ xt,
               const float* __restrict__ bias, float* __restrict__ out) {
    __shared__ __align__(16) short rowbuf[2][NW * C32];   // 2 x 16 KB

    const int bx   = blockIdx.x;                 // 0..247
    const int oy   = (bx & 7) * 31 + (bx >> 3);  // XCD-aware: contiguous oy per XCD
    const int b    = blockIdx.y;
    const int lane = threadIdx.x & 63;
    const int wv   = threadIdx.x >> 6;
    const int n    = lane & 15;
    const int quad = lane >> 4;
    const int x0w  = wv * 64;
    const int colb = x0w + n;

    f32x4 acc[MT][4];
    #pragma unroll
    for (int mt = 0; mt < MT; ++mt)
        #pragma unroll
        for (int nt = 0; nt < 4; ++nt)
            acc[mt][nt] = (f32x4){0.f, 0.f, 0.f, 0.f};

    const short* xbase = xt + ((size_t)b * NH + oy) * NW * C32;

    // prologue: stage row oy -> rowbuf[0] (4 chunks of 1 KB per wave)
    #pragma unroll
    for (int i = 0; i < 4; ++i) {
        const int chunk = i * 4 + wv;
        gll16(xbase + chunk * 512 + lane * 8, &rowbuf[0][chunk * 512]);
    }
    __syncthreads();   // compiler drains vmcnt(0) before s_barrier

    for (int ky = 0; ky < 9; ++ky) {
        const short* lrow = rowbuf[ky & 1];

        // stage next row early: 9 k-steps of cover before the barrier drain
        if (ky < 8) {
            const short* srcn = xbase + (size_t)(ky + 1) * NW * C32;
            short* ldst = rowbuf[(ky & 1) ^ 1];
            #pragma unroll
            for (int i = 0; i < 4; ++i) {
                const int chunk = i * 4 + wv;
                gll16(srcn + chunk * 512 + lane * 8, ldst + chunk * 512);
            }
        }

        const short* wky = wf + (size_t)ky * 9 * 3584 + lane * 8;

        bf16x8 a0[MT], a1[MT], b0[4], b1[4];
        LOADA(a0, 0); LOADB(b0, 0);
        LOADA(a1, 1); LOADB(b1, 1); MM(a0, b0);   // kx=0
        LOADA(a0, 2); LOADB(b0, 2); MM(a1, b1);   // kx=1
        LOADA(a1, 3); LOADB(b1, 3); MM(a0, b0);   // kx=2
        LOADA(a0, 4); LOADB(b0, 4); MM(a1, b1);   // kx=3
        LOADA(a1, 5); LOADB(b1, 5); MM(a0, b0);   // kx=4
        LOADA(a0, 6); LOADB(b0, 6); MM(a1, b1);   // kx=5
        LOADA(a1, 7); LOADB(b1, 7); MM(a0, b0);   // kx=6
        LOADA(a0, 8); LOADB(b0, 8); MM(a1, b1);   // kx=7
        MM(a0, b0);                               // kx=8

        if (ky < 8) __syncthreads();
    }

    // epilogue: C/D layout col = lane&15 (ox), row = quad*4 + r (oc)
    #pragma unroll
    for (int mt = 0; mt < MT; ++mt) {
        #pragma unroll
        for (int nt = 0; nt < 4; ++nt) {
            int ox = x0w + nt * 16 + n;
            if (ox >= OW) continue;
            #pragma unroll
            for (int r = 0; r < 4; ++r) {
                int oc = mt * 16 + quad * 4 + r;
                if (oc < NOC)
                    out[(((size_t)b * NOC + oc) * OH + oy) * OW + ox] =
                        acc[mt][nt][r] + bias[oc];
            }
        }
    }
}

extern "C" void kernel_launch(void* const* d_in, const int* in_sizes, int n_in,
                              void* d_out, int out_size, void* d_ws, size_t ws_size,
                              hipStream_t stream) {
    const float* pic  = (const float*)d_in[0];
    const float* wgt  = (const float*)d_in[1];
    const float* bias = (const float*)d_in[2];
    float* out        = (float*)d_out;

    short* wf = (short*)d_ws;
    short* xt = (short*)((char*)d_ws + XT_OFFSET);

    hipLaunchKernelGGL(prep, dim3(WF_BLOCKS + NB * NH), dim3(256), 0, stream,
                       wgt, pic, wf, xt);
    hipLaunchKernelGGL(conv_mfma, dim3(OH, NB), dim3(256), 0, stream, wf, xt, bias, out);
}